// Round 9
// baseline (124.858 us; speedup 1.0000x reference)
//
#include <hip/hip_runtime.h>
#include <hip/hip_bf16.h>

#define T_TOKENS 2048
#define D_EMBD   1024
#define N_EXP    8
#define TOTAL_W  12288
#define CAP      2048
#define CAPH     2048

typedef __attribute__((ext_vector_type(8))) short bf16x8;
typedef __attribute__((ext_vector_type(4))) float f32x4;
typedef __attribute__((ext_vector_type(4))) unsigned short u16x4;
typedef __attribute__((ext_vector_type(8))) unsigned short u16x8;

__device__ __constant__ int d_OFF[N_EXP] = {0,1024,2048,3072,4096,6144,8192,10240};
__device__ __constant__ int d_WID[N_EXP] = {1024,1024,1024,1024,2048,2048,2048,2048};

// workspace layout (bytes). cnt: 8 counters at 128B stride.
#define WS_TOK   1024
#define WS_SLK   (WS_TOK + N_EXP*CAP*4)
#define WS_WGT   (WS_SLK + N_EXP*CAP*4)
#define WS_WG2   (WS_WGT + N_EXP*CAP*4)
#define WS_XB    (WS_WG2 + T_TOKENS*2*4)
#define WS_W1B   (WS_XB + T_TOKENS*D_EMBD*2)
#define WS_W2B   (WS_W1B + D_EMBD*TOTAL_W*2)
#define WS_H     (WS_W2B + (size_t)TOTAL_W*D_EMBD*2)
#define WS_END   (WS_H + (size_t)TOTAL_W*CAPH*2)
#define WS_Y     WS_XB   // Y[4096][1024] f32 (16MB) aliases XB+W1B (dead when gemm2 runs)

__device__ __forceinline__ void gload_lds16(const void* g, void* l) {
    __builtin_amdgcn_global_load_lds(
        (const __attribute__((address_space(1))) void*)g,
        (__attribute__((address_space(3))) void*)l, 16, 0, 0);
}

__device__ __forceinline__ unsigned short f2bf(float f) {
    __hip_bfloat16 h = __float2bfloat16(f);
    return *reinterpret_cast<unsigned short*>(&h);
}

// ---- router body: routes 32 tokens, records slot->token, slot->(2t+k), per-(t,k) weight ----
__device__ __forceinline__ void router_body(
    int rb, int tid, char* smem,
    const float* __restrict__ x, const float* __restrict__ rw,
    int* __restrict__ cnt, int* __restrict__ tok, int* __restrict__ slotk,
    float* __restrict__ wgtl, float* __restrict__ wgt2)
{
    float* rws   = (float*)smem;               // 32768 B
    int*   lcnt  = (int*)(smem + 32768);
    int*   lbase = (int*)(smem + 32800);
    int   (*ltok)[32] = (int(*)[32])(smem + 32832);
    float (*lwgt)[32] = (float(*)[32])(smem + 33856);
    int   (*lkk)[32]  = (int(*)[32])(smem + 34880);

    const int wv = tid >> 6, lane = tid & 63;
    {
        const float4* src = (const float4*)rw;
        float4* dst = (float4*)rws;
        for (int i = tid; i < N_EXP * 256; i += 256) dst[i] = src[i];
    }
    if (tid < N_EXP) lcnt[tid] = 0;
    __syncthreads();

    const float4* x4 = (const float4*)x;
    for (int ts = 0; ts < 8; ++ts) {
        const int t = rb * 32 + wv * 8 + ts;
        float4 xv[4];
#pragma unroll
        for (int i = 0; i < 4; ++i) xv[i] = x4[(size_t)t * 256 + lane + 64 * i];
        float acc[N_EXP];
#pragma unroll
        for (int e = 0; e < N_EXP; ++e) {
            float a = 0.f;
#pragma unroll
            for (int i = 0; i < 4; ++i) {
                float4 w4 = ((const float4*)(rws + e * 1024))[lane + 64 * i];
                a += xv[i].x * w4.x + xv[i].y * w4.y + xv[i].z * w4.z + xv[i].w * w4.w;
            }
            acc[e] = a;
        }
#pragma unroll
        for (int e = 0; e < N_EXP; ++e)
#pragma unroll
            for (int o = 32; o > 0; o >>= 1) acc[e] += __shfl_xor(acc[e], o, 64);

        if (lane == 0) {
            float p[N_EXP];
#pragma unroll
            for (int e = 0; e < N_EXP; ++e) p[e] = 1.f / (1.f + __expf(-acc[e]));
            int e0 = 0;
#pragma unroll
            for (int e = 1; e < N_EXP; ++e) if (p[e] > p[e0]) e0 = e;
            int e1 = (e0 == 0) ? 1 : 0;
#pragma unroll
            for (int e = 0; e < N_EXP; ++e) if (e != e0 && p[e] > p[e1]) e1 = e;
            float w0 = p[e0], w1 = p[e1], s = w0 + w1 + 1e-20f;
            int s0 = atomicAdd(&lcnt[e0], 1);
            ltok[e0][s0] = t;  lwgt[e0][s0] = w0 / s;  lkk[e0][s0] = 0;
            int s1 = atomicAdd(&lcnt[e1], 1);
            ltok[e1][s1] = t;  lwgt[e1][s1] = w1 / s;  lkk[e1][s1] = 1;
        }
    }
    __syncthreads();
    if (tid < N_EXP) lbase[tid] = atomicAdd(&cnt[tid << 5], lcnt[tid]);
    __syncthreads();
    {
        const int e = tid >> 5, i = tid & 31;
        if (i < lcnt[e]) {
            int dst = e * CAP + lbase[e] + i;
            int t   = ltok[e][i], k = lkk[e][i];
            tok[dst]   = t;
            wgtl[dst]  = lwgt[e][i];
            slotk[dst] = t * 2 + k;
            wgt2[t * 2 + k] = lwgt[e][i];
        }
    }
}

// ---- router(64 blocks) + x->bf16 (1024 blocks) ----
__global__ __launch_bounds__(256) void router_convx_kernel(
    const float* __restrict__ x, const float* __restrict__ rw,
    int* __restrict__ cnt, int* __restrict__ tok, int* __restrict__ slotk,
    float* __restrict__ wgtl, float* __restrict__ wgt2,
    __hip_bfloat16* __restrict__ xb)
{
    __shared__ __align__(16) char smem[35904];
    const int bx = blockIdx.x, tid = threadIdx.x;
    if (bx < 64) {
        router_body(bx, tid, smem, x, rw, cnt, tok, slotk, wgtl, wgt2);
    } else {
        int i4 = (bx - 64) * 512 + tid * 2;
        const float4 v0 = reinterpret_cast<const float4*>(x)[i4];
        const float4 v1 = reinterpret_cast<const float4*>(x)[i4 + 1];
        u16x8 o;
        o[0] = f2bf(v0.x); o[1] = f2bf(v0.y); o[2] = f2bf(v0.z); o[3] = f2bf(v0.w);
        o[4] = f2bf(v1.x); o[5] = f2bf(v1.y); o[6] = f2bf(v1.z); o[7] = f2bf(v1.w);
        *reinterpret_cast<u16x8*>(xb + (size_t)i4 * 4) = o;
    }
}

// ---- transpose both weights: 16.6KB LDS (9 blocks/CU), u16x8 stores ----
// blocks [0,3072): w1 (R=1024, C=12288); [3072,6144): w2 (R=12288, C=1024)
__global__ __launch_bounds__(256) void transpose_kernel(
    const float* __restrict__ w1, const float* __restrict__ w2,
    __hip_bfloat16* __restrict__ w1b, __hip_bfloat16* __restrict__ w2b)
{
    __shared__ float ls[64][65];
    const int bx = blockIdx.x, tid = threadIdx.x;
    const float* in; __hip_bfloat16* out; int R, C, br, bc;
    if (bx < 3072) { in = w1; out = w1b; R = D_EMBD;  C = TOTAL_W; br = bx / 192; bc = bx % 192; }
    else { int b2 = bx - 3072; in = w2; out = w2b; R = TOTAL_W; C = D_EMBD; br = b2 / 16; bc = b2 % 16; }
    const int r0 = br << 6, c0 = bc << 6;

#pragma unroll
    for (int i = 0; i < 4; ++i) {
        int flat = i * 1024 + tid * 4;
        int r = flat >> 6, c = flat & 63;
        float4 v = *reinterpret_cast<const float4*>(&in[(size_t)(r0 + r) * C + c0 + c]);
        ls[r][c] = v.x; ls[r][c + 1] = v.y; ls[r][c + 2] = v.z; ls[r][c + 3] = v.w;
    }
    __syncthreads();
#pragma unroll
    for (int i = 0; i < 2; ++i) {
        int flat = i * 2048 + tid * 8;
        int cc = flat >> 6, rr = flat & 63;
        u16x8 o;
#pragma unroll
        for (int q = 0; q < 8; ++q) o[q] = f2bf(ls[rr + q][cc]);
        *reinterpret_cast<u16x8*>(&out[(size_t)(c0 + cc) * R + r0 + rr]) = o;
    }
}

// standalone router for fallback path
__global__ __launch_bounds__(256) void router2_kernel(
    const float* __restrict__ x, const float* __restrict__ rw,
    int* __restrict__ cnt, int* __restrict__ tok, int* __restrict__ slotk,
    float* __restrict__ wgtl, float* __restrict__ wgt2)
{
    __shared__ __align__(16) char smem[35904];
    router_body(blockIdx.x, threadIdx.x, smem, x, rw, cnt, tok, slotk, wgtl, wgt2);
}

// -------- GEMM1: H = relu(X @ W1)^2 ; 64x128 tile, dbuf, counted vmcnt --------
__global__ __launch_bounds__(256) void gemm1_kernel(
    const char* __restrict__ xb, const char* __restrict__ w1b,
    const int* __restrict__ cnt, const int* __restrict__ tok,
    __hip_bfloat16* __restrict__ H)
{
    int bx0 = blockIdx.x;
    int bx = (bx0 & 7) * 384 + (bx0 >> 3);   // XCD chunk swizzle (3072 = 8*384)
    int e, tt, nT;
    if (bx < 2048) {                          // wide experts FIRST (longer blocks)
        e = 4 + (bx >> 9); int r = bx & 511; tt = r >> 4; nT = r & 15;
    } else {
        int b2 = bx - 2048; e = b2 >> 8; int r = b2 & 255; tt = r >> 3; nT = r & 7;
    }
    const int nt = cnt[e << 5];
    if (tt * 64 >= nt) return;

    const int we  = d_WID[e];
    const int n0  = nT * 128;
    const int tid = threadIdx.x;
    const int wv  = tid >> 6, lane = tid & 63;
    const int wr  = wv >> 1, wc = wv & 1;

    __shared__ __align__(16) char lds[2][24576];  // A: [0,8K) 64x64; B: [8K,24K) 128x64
    __shared__ int ts_s[64];

    if (tid < 64) {
        int s = tt * 64 + tid;
        ts_s[tid] = (s < nt) ? tok[e * CAP + s] : 0;
    }
    __syncthreads();

    f32x4 acc[2][4];
#pragma unroll
    for (int mi = 0; mi < 2; ++mi)
#pragma unroll
        for (int nj = 0; nj < 4; ++nj) acc[mi][nj] = (f32x4){0.f,0.f,0.f,0.f};

    const char* w1row = w1b + (size_t)(d_OFF[e] + n0) * 2048;

    auto STAGE = [&](int buf, int ks) {
        const int k0b = ks * 128;
#pragma unroll
        for (int j = 0; j < 6; ++j) {
            const int flat = j * 4096 + tid * 16;
            char* dst = lds[buf] + flat;
            if (flat < 8192) {
                int r = flat >> 7, cb = flat & 127;
                gload_lds16(xb + (size_t)ts_s[r] * 2048 + k0b + (cb ^ ((r & 7) << 4)), dst);
            } else {
                int f2 = flat - 8192, n = f2 >> 7, cb = f2 & 127;
                gload_lds16(w1row + (size_t)n * 2048 + k0b + (cb ^ ((n & 7) << 4)), dst);
            }
        }
    };
    auto COMPUTE = [&](int buf) {
        const char* LA = lds[buf];
        const char* LB = lds[buf] + 8192;
#pragma unroll
        for (int ksl = 0; ksl < 2; ++ksl) {
            const int kb = ksl * 64 + (lane >> 4) * 16;
            bf16x8 a[2], b[4];
#pragma unroll
            for (int mi = 0; mi < 2; ++mi) {
                int row = wr * 32 + mi * 16 + (lane & 15);
                a[mi] = *(const bf16x8*)(LA + row * 128 + (kb ^ ((row & 7) << 4)));
            }
#pragma unroll
            for (int nj = 0; nj < 4; ++nj) {
                int n = wc * 64 + nj * 16 + (lane & 15);
                b[nj] = *(const bf16x8*)(LB + n * 128 + (kb ^ ((n & 7) << 4)));
            }
#pragma unroll
            for (int mi = 0; mi < 2; ++mi)
#pragma unroll
                for (int nj = 0; nj < 4; ++nj)
                    acc[mi][nj] = __builtin_amdgcn_mfma_f32_16x16x32_bf16(
                        a[mi], b[nj], acc[mi][nj], 0, 0, 0);
        }
    };

    STAGE(0, 0);
    int cur = 0;
    for (int ks = 0; ks < 16; ++ks) {
        if (ks + 1 < 16) {
            STAGE(cur ^ 1, ks + 1);
            asm volatile("s_waitcnt vmcnt(6)" ::: "memory");   // cur done; next in flight
        } else {
            asm volatile("s_waitcnt vmcnt(0)" ::: "memory");
        }
        __builtin_amdgcn_s_barrier();
        __builtin_amdgcn_sched_barrier(0);
        COMPUTE(cur);
        __builtin_amdgcn_sched_barrier(0);
        __builtin_amdgcn_s_barrier();
        cur ^= 1;
    }

    const size_t hbase = (size_t)d_OFF[e] * CAPH;
#pragma unroll
    for (int mi = 0; mi < 2; ++mi)
#pragma unroll
        for (int q = 0; q < 4; ++q) {
            int row  = wr * 32 + mi * 16 + (lane >> 4) * 4 + q;
            int slot = tt * 64 + row;
            __hip_bfloat16* hp = H + hbase + (size_t)slot * we + n0 + wc * 64 + (lane & 15);
#pragma unroll
            for (int nj = 0; nj < 4; ++nj) {
                float v = fmaxf(acc[mi][nj][q], 0.f);
                hp[nj * 16] = __float2bfloat16(v * v);
            }
        }
}

// -------- GEMM2: Y[2t+k] = H @ W2 (raw f32 partials, no atomics) --------
__global__ __launch_bounds__(256) void gemm2_kernel(
    const char* __restrict__ Hb, const char* __restrict__ w2b,
    const int* __restrict__ cnt, const int* __restrict__ slotk,
    float* __restrict__ Y)
{
    int bx0 = blockIdx.x;
    int bx = (bx0 & 7) * 256 + (bx0 >> 3);   // 2048 = 8*256
    int e, tt, nT;
    if (bx < 1024) {                          // wide experts first (32 K-steps)
        e = 4 + (bx >> 8); int r = bx & 255; tt = r >> 3; nT = r & 7;
    } else {
        int b2 = bx - 1024; e = b2 >> 8; int r = b2 & 255; tt = r >> 3; nT = r & 7;
    }
    const int nt = cnt[e << 5];
    if (tt * 64 >= nt) return;

    const int we  = d_WID[e];
    const int n0  = nT * 128;
    const int tid = threadIdx.x;
    const int wv  = tid >> 6, lane = tid & 63;
    const int wr  = wv >> 1, wc = wv & 1;

    __shared__ __align__(16) char lds[2][24576];
    __shared__ int yk_s[64];

    if (tid < 64) {
        int s = tt * 64 + tid;
        yk_s[tid] = (s < nt) ? slotk[e * CAP + s] : 0;
    }
    __syncthreads();

    f32x4 acc[2][4];
#pragma unroll
    for (int mi = 0; mi < 2; ++mi)
#pragma unroll
        for (int nj = 0; nj < 4; ++nj) acc[mi][nj] = (f32x4){0.f,0.f,0.f,0.f};

    const char* Habase = Hb + ((size_t)d_OFF[e] * CAPH + (size_t)tt * 64 * we) * 2;
    const char* w2base = w2b + ((size_t)n0 * TOTAL_W + d_OFF[e]) * 2;
    const int   ksteps = we >> 6;

    auto STAGE = [&](int buf, int ks) {
        const int k0b = ks * 128;
#pragma unroll
        for (int j = 0; j < 6; ++j) {
            const int flat = j * 4096 + tid * 16;
            char* dst = lds[buf] + flat;
            if (flat < 8192) {
                int r = flat >> 7, cb = flat & 127;
                gload_lds16(Habase + (size_t)r * (we * 2) + k0b + (cb ^ ((r & 7) << 4)), dst);
            } else {
                int f2 = flat - 8192, n = f2 >> 7, cb = f2 & 127;
                gload_lds16(w2base + (size_t)n * (TOTAL_W * 2) + k0b + (cb ^ ((n & 7) << 4)), dst);
            }
        }
    };
    auto COMPUTE = [&](int buf) {
        const char* LA = lds[buf];
        const char* LB = lds[buf] + 8192;
#pragma unroll
        for (int ksl = 0; ksl < 2; ++ksl) {
            const int kb = ksl * 64 + (lane >> 4) * 16;
            bf16x8 a[2], b[4];
#pragma unroll
            for (int mi = 0; mi < 2; ++mi) {
                int row = wr * 32 + mi * 16 + (lane & 15);
                a[mi] = *(const bf16x8*)(LA + row * 128 + (kb ^ ((row & 7) << 4)));
            }
#pragma unroll
            for (int nj = 0; nj < 4; ++nj) {
                int n = wc * 64 + nj * 16 + (lane & 15);
                b[nj] = *(const bf16x8*)(LB + n * 128 + (kb ^ ((n & 7) << 4)));
            }
#pragma unroll
            for (int mi = 0; mi < 2; ++mi)
#pragma unroll
                for (int nj = 0; nj < 4; ++nj)
                    acc[mi][nj] = __builtin_amdgcn_mfma_f32_16x16x32_bf16(
                        a[mi], b[nj], acc[mi][nj], 0, 0, 0);
        }
    };

    STAGE(0, 0);
    int cur = 0;
    for (int ks = 0; ks < ksteps; ++ks) {
        if (ks + 1 < ksteps) {
            STAGE(cur ^ 1, ks + 1);
            asm volatile("s_waitcnt vmcnt(6)" ::: "memory");
        } else {
            asm volatile("s_waitcnt vmcnt(0)" ::: "memory");
        }
        __builtin_amdgcn_s_barrier();
        __builtin_amdgcn_sched_barrier(0);
        COMPUTE(cur);
        __builtin_amdgcn_sched_barrier(0);
        __builtin_amdgcn_s_barrier();
        cur ^= 1;
    }

#pragma unroll
    for (int mi = 0; mi < 2; ++mi)
#pragma unroll
        for (int q = 0; q < 4; ++q) {
            int row  = wr * 32 + mi * 16 + (lane >> 4) * 4 + q;
            int slot = tt * 64 + row;
            if (slot < nt) {
                float* yp = Y + (size_t)yk_s[row] * D_EMBD + n0 + wc * 64 + (lane & 15);
#pragma unroll
                for (int nj = 0; nj < 4; ++nj)
                    yp[nj * 16] = acc[mi][nj][q];
            }
        }
}

// -------- gather: out[t] = w0*Y[2t] + w1*Y[2t+1] --------
__global__ __launch_bounds__(256) void gather_kernel(
    const float* __restrict__ Y, const float* __restrict__ wgt2,
    float* __restrict__ out)
{
    const int t = blockIdx.x, tid = threadIdx.x;
    const float w0 = wgt2[t * 2], w1 = wgt2[t * 2 + 1];
    const float4 y0 = reinterpret_cast<const float4*>(Y + (size_t)(t * 2) * D_EMBD)[tid];
    const float4 y1 = reinterpret_cast<const float4*>(Y + (size_t)(t * 2 + 1) * D_EMBD)[tid];
    float4 o;
    o.x = w0 * y0.x + w1 * y1.x;  o.y = w0 * y0.y + w1 * y1.y;
    o.z = w0 * y0.z + w1 * y1.z;  o.w = w0 * y0.w + w1 * y1.w;
    reinterpret_cast<float4*>(out + (size_t)t * D_EMBD)[tid] = o;
}

// -------- fp32 fallback (if ws too small) --------
__global__ __launch_bounds__(256, 3) void moe_group_kernel(
    const float* __restrict__ x, const float* __restrict__ w1,
    const float* __restrict__ w2, const int* __restrict__ cnt,
    const int* __restrict__ tok, const float* __restrict__ wgtl,
    float* __restrict__ out)
{
    int e, tt, colh, wh, nwh;
    int bx = blockIdx.x;
    if (bx < 1024) { e = bx >> 8; int rem = bx & 255; wh = rem & 1; colh = (rem >> 1) & 1; tt = rem >> 2; nwh = 2; }
    else { int b2 = bx - 1024; e = 4 + (b2 >> 9); int rem = b2 & 511; wh = rem & 3; colh = (rem >> 2) & 1; tt = rem >> 3; nwh = 4; }
    const int nt = cnt[e << 5];
    if (tt * 32 >= nt) return;

    const int tid = threadIdx.x;
    const int off = d_OFF[e];
    const int wtn = d_WID[e] >> 7;
    const int wpb = wtn / nwh;
    const int wt0 = wh * wpb;

    __shared__ float xs[128][36];
    __shared__ float hs[128][36];
    __shared__ int   ts_s[32];
    __shared__ float wg_s[32];

    if (tid < 32) {
        int s = tt * 32 + tid;
        ts_s[tid] = (s < nt) ? tok[e * CAP + s] : 0;
        wg_s[tid] = (s < nt) ? wgtl[e * CAP + s] : 0.f;
    }

    const int tg = tid >> 5, cg = tid & 31;
    float acc_dn[4][16];
#pragma unroll
    for (int a = 0; a < 4; ++a)
#pragma unroll
        for (int m = 0; m < 16; ++m) acc_dn[a][m] = 0.f;

    for (int wt = wt0; wt < wt0 + wpb; ++wt) {
        float au[4][4];
#pragma unroll
        for (int a = 0; a < 4; ++a)
#pragma unroll
            for (int b = 0; b < 4; ++b) au[a][b] = 0.f;
        const int cw1 = off + wt * 128 + cg * 4;
        for (int dc = 0; dc < 8; ++dc) {
            const int d0 = dc * 128;
            __syncthreads();
#pragma unroll
            for (int r = 0; r < 16; ++r) {
                int flat = r * 256 + tid, ii = flat & 127, t = flat >> 7;
                xs[ii][t] = x[(size_t)ts_s[t] * D_EMBD + d0 + ii];
            }
            __syncthreads();
            const float* pw = w1 + (size_t)d0 * TOTAL_W + cw1;
            for (int ii = 0; ii < 128; ++ii) {
                const float4 xv = *reinterpret_cast<const float4*>(&xs[ii][tg * 4]);
                const float4 wv = *reinterpret_cast<const float4*>(pw);
                pw += TOTAL_W;
                const float xa[4] = {xv.x, xv.y, xv.z, xv.w};
                const float wb[4] = {wv.x, wv.y, wv.z, wv.w};
#pragma unroll
                for (int a = 0; a < 4; ++a)
#pragma unroll
                    for (int b = 0; b < 4; ++b) au[a][b] += xa[a] * wb[b];
            }
        }
#pragma unroll
        for (int b = 0; b < 4; ++b) {
            float4 v;
            float r0 = fmaxf(au[0][b], 0.f), r1 = fmaxf(au[1][b], 0.f);
            float r2 = fmaxf(au[2][b], 0.f), r3 = fmaxf(au[3][b], 0.f);
            v.x = r0 * r0; v.y = r1 * r1; v.z = r2 * r2; v.w = r3 * r3;
            *reinterpret_cast<float4*>(&hs[cg * 4 + b][tg * 4]) = v;
        }
        __syncthreads();
        const float* pw2 = w2 + (size_t)(off + wt * 128) * D_EMBD + colh * 512 + cg * 4;
        for (int j = 0; j < 128; ++j) {
            const float4 hv = *reinterpret_cast<const float4*>(&hs[j][tg * 4]);
            const float ha[4] = {hv.x, hv.y, hv.z, hv.w};
            const float* row = pw2 + (size_t)j * D_EMBD;
#pragma unroll
            for (int b = 0; b < 4; ++b) {
                const float4 wv = *reinterpret_cast<const float4*>(row + b * 128);
                const float wq[4] = {wv.x, wv.y, wv.z, wv.w};
#pragma unroll
                for (int a = 0; a < 4; ++a)
#pragma unroll
                    for (int q = 0; q < 4; ++q)
                        acc_dn[a][b * 4 + q] += ha[a] * wq[q];
            }
        }
        __syncthreads();
    }
#pragma unroll
    for (int a = 0; a < 4; ++a) {
        const int   t  = ts_s[tg * 4 + a];
        const float wg = wg_s[tg * 4 + a];
        float* ot = out + (size_t)t * D_EMBD + colh * 512 + cg * 4;
#pragma unroll
        for (int b = 0; b < 4; ++b)
#pragma unroll
            for (int q = 0; q < 4; ++q)
                atomicAdd(&ot[b * 128 + q], wg * acc_dn[a][b * 4 + q]);
    }
}

extern "C" void kernel_launch(void* const* d_in, const int* in_sizes, int n_in,
                              void* d_out, int out_size, void* d_ws, size_t ws_size,
                              hipStream_t stream) {
    const float* x  = (const float*)d_in[0];
    const float* rw = (const float*)d_in[1];
    const float* w1 = (const float*)d_in[2];
    const float* w2 = (const float*)d_in[3];
    float* out = (float*)d_out;

    char*  ws    = (char*)d_ws;
    int*   cnt   = (int*)ws;                    // 8 counters, 128B apart
    int*   tokl  = (int*)(ws + WS_TOK);
    int*   slotk = (int*)(ws + WS_SLK);
    float* wgtl  = (float*)(ws + WS_WGT);
    float* wgt2  = (float*)(ws + WS_WG2);

    hipMemsetAsync(d_ws, 0, 1024, stream);

    if (ws_size >= WS_END) {
        __hip_bfloat16* xb  = (__hip_bfloat16*)(ws + WS_XB);
        __hip_bfloat16* w1b = (__hip_bfloat16*)(ws + WS_W1B);
        __hip_bfloat16* w2b = (__hip_bfloat16*)(ws + WS_W2B);
        __hip_bfloat16* H   = (__hip_bfloat16*)(ws + WS_H);
        float*          Y   = (float*)(ws + WS_Y);   // aliases XB/W1B (dead post-gemm1)

        router_convx_kernel<<<1088, 256, 0, stream>>>(x, rw, cnt, tokl, slotk, wgtl, wgt2, xb);
        transpose_kernel<<<6144, 256, 0, stream>>>(w1, w2, w1b, w2b);
        gemm1_kernel<<<3072, 256, 0, stream>>>((const char*)xb, (const char*)w1b, cnt, tokl, H);
        gemm2_kernel<<<2048, 256, 0, stream>>>((const char*)H, (const char*)w2b, cnt, slotk, Y);
        gather_kernel<<<T_TOKENS, 256, 0, stream>>>(Y, wgt2, out);
    } else {
        hipMemsetAsync(d_out, 0, (size_t)out_size * sizeof(float), stream);
        router2_kernel<<<T_TOKENS / 32, 256, 0, stream>>>(x, rw, cnt, tokl, slotk, wgtl, wgt2);
        moe_group_kernel<<<1024 + 2048, 256, 0, stream>>>(x, w1, w2, cnt, tokl, wgtl, out);
    }
}

// Round 10
// 100.474 us; speedup vs baseline: 1.2427x; 1.2427x over previous
//
#include <hip/hip_runtime.h>
#include <hip/hip_bf16.h>

#define T_TOKENS 2048
#define D_EMBD   1024
#define N_EXP    8
#define TOTAL_W  12288
#define CAP      2048
#define CAPH     2048

typedef __attribute__((ext_vector_type(8))) short bf16x8;
typedef __attribute__((ext_vector_type(4))) float f32x4;
typedef __attribute__((ext_vector_type(4))) unsigned short u16x4;
typedef __attribute__((ext_vector_type(8))) unsigned short u16x8;

__device__ __constant__ int d_OFF[N_EXP] = {0,1024,2048,3072,4096,6144,8192,10240};
__device__ __constant__ int d_WID[N_EXP] = {1024,1024,1024,1024,2048,2048,2048,2048};

// workspace layout (bytes). cnt: 8 counters at 128B stride.
#define WS_TOK   1024
#define WS_SLK   (WS_TOK + N_EXP*CAP*4)
#define WS_WGT   (WS_SLK + N_EXP*CAP*4)
#define WS_WG2   (WS_WGT + N_EXP*CAP*4)
#define WS_XB    (WS_WG2 + T_TOKENS*2*4)
#define WS_W1B   (WS_XB + T_TOKENS*D_EMBD*2)
#define WS_W2B   (WS_W1B + D_EMBD*TOTAL_W*2)
#define WS_H     (WS_W2B + (size_t)TOTAL_W*D_EMBD*2)
#define WS_END   (WS_H + (size_t)TOTAL_W*CAPH*2)
#define WS_Y     WS_XB   // Y[4096][1024] f32 (16MB) aliases XB+W1B (dead when gemm2 runs)

__device__ __forceinline__ void gload_lds16(const void* g, void* l) {
    __builtin_amdgcn_global_load_lds(
        (const __attribute__((address_space(1))) void*)g,
        (__attribute__((address_space(3))) void*)l, 16, 0, 0);
}

__device__ __forceinline__ unsigned short f2bf(float f) {
    __hip_bfloat16 h = __float2bfloat16(f);
    return *reinterpret_cast<unsigned short*>(&h);
}

// -------- zero counters (replaces runtime fillBuffer path) --------
__global__ __launch_bounds__(64) void zero_kernel(int* __restrict__ cnt) {
    if (threadIdx.x < N_EXP) cnt[threadIdx.x << 5] = 0;
}

// ---- router body (no rw LDS staging; rw reads hit L1 after first token).
// smem needs only ~3.2 KB of bucket arrays. ----
__device__ __forceinline__ void router_body(
    int rb, int tid, char* smem,
    const float* __restrict__ x, const float* __restrict__ rw,
    int* __restrict__ cnt, int* __restrict__ tok, int* __restrict__ slotk,
    float* __restrict__ wgtl, float* __restrict__ wgt2)
{
    int*   lcnt  = (int*)smem;                  // 32 B
    int*   lbase = (int*)(smem + 32);           // 32 B
    int   (*ltok)[32] = (int(*)[32])(smem + 64);
    float (*lwgt)[32] = (float(*)[32])(smem + 64 + 1024);
    int   (*lkk)[32]  = (int(*)[32])(smem + 64 + 2048);

    const int wv = tid >> 6, lane = tid & 63;
    if (tid < N_EXP) lcnt[tid] = 0;
    __syncthreads();

    const float4* x4  = (const float4*)x;
    const float4* rw4 = (const float4*)rw;
    for (int ts = 0; ts < 8; ++ts) {
        const int t = rb * 32 + wv * 8 + ts;
        float4 xv[4];
#pragma unroll
        for (int i = 0; i < 4; ++i) xv[i] = x4[(size_t)t * 256 + lane + 64 * i];
        float acc[N_EXP];
#pragma unroll
        for (int e = 0; e < N_EXP; ++e) {
            float a = 0.f;
#pragma unroll
            for (int i = 0; i < 4; ++i) {
                float4 w4 = rw4[e * 256 + lane + 64 * i];
                a += xv[i].x * w4.x + xv[i].y * w4.y + xv[i].z * w4.z + xv[i].w * w4.w;
            }
            acc[e] = a;
        }
#pragma unroll
        for (int e = 0; e < N_EXP; ++e)
#pragma unroll
            for (int o = 32; o > 0; o >>= 1) acc[e] += __shfl_xor(acc[e], o, 64);

        if (lane == 0) {
            float p[N_EXP];
#pragma unroll
            for (int e = 0; e < N_EXP; ++e) p[e] = 1.f / (1.f + __expf(-acc[e]));
            int e0 = 0;
#pragma unroll
            for (int e = 1; e < N_EXP; ++e) if (p[e] > p[e0]) e0 = e;
            int e1 = (e0 == 0) ? 1 : 0;
#pragma unroll
            for (int e = 0; e < N_EXP; ++e) if (e != e0 && p[e] > p[e1]) e1 = e;
            float w0 = p[e0], w1 = p[e1], s = w0 + w1 + 1e-20f;
            int s0 = atomicAdd(&lcnt[e0], 1);
            ltok[e0][s0] = t;  lwgt[e0][s0] = w0 / s;  lkk[e0][s0] = 0;
            int s1 = atomicAdd(&lcnt[e1], 1);
            ltok[e1][s1] = t;  lwgt[e1][s1] = w1 / s;  lkk[e1][s1] = 1;
        }
    }
    __syncthreads();
    if (tid < N_EXP) lbase[tid] = atomicAdd(&cnt[tid << 5], lcnt[tid]);
    __syncthreads();
    {
        const int e = tid >> 5, i = tid & 31;
        if (i < lcnt[e]) {
            int dst = e * CAP + lbase[e] + i;
            int t   = ltok[e][i], k = lkk[e][i];
            tok[dst]   = t;
            wgtl[dst]  = lwgt[e][i];
            slotk[dst] = t * 2 + k;
            wgt2[t * 2 + k] = lwgt[e][i];
        }
    }
}

__device__ __forceinline__ void transpose_body(
    const float* __restrict__ in, __hip_bfloat16* __restrict__ out,
    int R, int C, int br, int bc, int tid, char* smem)
{
    float (*ls)[65] = (float(*)[65])smem;
    const int r0 = br << 6, c0 = bc << 6;
#pragma unroll
    for (int i = 0; i < 4; ++i) {
        int flat = i * 1024 + tid * 4;
        int r = flat >> 6, c = flat & 63;
        float4 v = *reinterpret_cast<const float4*>(&in[(size_t)(r0 + r) * C + c0 + c]);
        ls[r][c] = v.x; ls[r][c + 1] = v.y; ls[r][c + 2] = v.z; ls[r][c + 3] = v.w;
    }
    __syncthreads();
#pragma unroll
    for (int i = 0; i < 2; ++i) {
        int flat = i * 2048 + tid * 8;
        int cc = flat >> 6, rr = flat & 63;
        u16x8 o;
#pragma unroll
        for (int q = 0; q < 8; ++q) o[q] = f2bf(ls[rr + q][cc]);
        *reinterpret_cast<u16x8*>(&out[(size_t)(c0 + cc) * R + r0 + rr]) = o;
    }
}

// ---- prep2: router(64) + convx(1024) + w1T(3072) + w2T(3072), 16.6KB union LDS ----
__global__ __launch_bounds__(256) void prep2_kernel(
    const float* __restrict__ x, const float* __restrict__ rw,
    const float* __restrict__ w1, const float* __restrict__ w2,
    int* __restrict__ cnt, int* __restrict__ tok, int* __restrict__ slotk,
    float* __restrict__ wgtl, float* __restrict__ wgt2,
    __hip_bfloat16* __restrict__ xb, __hip_bfloat16* __restrict__ w1b,
    __hip_bfloat16* __restrict__ w2b)
{
    __shared__ __align__(16) char smem[16640];
    const int bx = blockIdx.x, tid = threadIdx.x;
    if (bx < 64) {
        router_body(bx, tid, smem, x, rw, cnt, tok, slotk, wgtl, wgt2);
    } else if (bx < 1088) {
        int i4 = (bx - 64) * 512 + tid * 2;
        const float4 v0 = reinterpret_cast<const float4*>(x)[i4];
        const float4 v1 = reinterpret_cast<const float4*>(x)[i4 + 1];
        u16x8 o;
        o[0] = f2bf(v0.x); o[1] = f2bf(v0.y); o[2] = f2bf(v0.z); o[3] = f2bf(v0.w);
        o[4] = f2bf(v1.x); o[5] = f2bf(v1.y); o[6] = f2bf(v1.z); o[7] = f2bf(v1.w);
        *reinterpret_cast<u16x8*>(xb + (size_t)i4 * 4) = o;
    } else if (bx < 4160) {
        int tb = bx - 1088;
        transpose_body(w1, w1b, D_EMBD, TOTAL_W, tb / 192, tb % 192, tid, smem);
    } else {
        int tb = bx - 4160;
        transpose_body(w2, w2b, TOTAL_W, D_EMBD, tb / 16, tb % 16, tid, smem);
    }
}

// standalone router for fallback path
__global__ __launch_bounds__(256) void router2_kernel(
    const float* __restrict__ x, const float* __restrict__ rw,
    int* __restrict__ cnt, int* __restrict__ tok, int* __restrict__ slotk,
    float* __restrict__ wgtl, float* __restrict__ wgt2)
{
    __shared__ __align__(16) char smem[16640];
    router_body(blockIdx.x, threadIdx.x, smem, x, rw, cnt, tok, slotk, wgtl, wgt2);
}

// -------- GEMM1: H = relu(X @ W1)^2 ; 64x128 tile, dbuf, counted vmcnt --------
__global__ __launch_bounds__(256) void gemm1_kernel(
    const char* __restrict__ xb, const char* __restrict__ w1b,
    const int* __restrict__ cnt, const int* __restrict__ tok,
    __hip_bfloat16* __restrict__ H)
{
    int bx0 = blockIdx.x;
    int bx = (bx0 & 7) * 384 + (bx0 >> 3);   // XCD chunk swizzle (3072 = 8*384)
    int e, tt, nT;
    if (bx < 2048) {                          // wide experts FIRST (longer blocks)
        e = 4 + (bx >> 9); int r = bx & 511; tt = r >> 4; nT = r & 15;
    } else {
        int b2 = bx - 2048; e = b2 >> 8; int r = b2 & 255; tt = r >> 3; nT = r & 7;
    }
    const int nt = cnt[e << 5];
    if (tt * 64 >= nt) return;

    const int we  = d_WID[e];
    const int n0  = nT * 128;
    const int tid = threadIdx.x;
    const int wv  = tid >> 6, lane = tid & 63;
    const int wr  = wv >> 1, wc = wv & 1;

    __shared__ __align__(16) char lds[2][24576];  // A: [0,8K) 64x64; B: [8K,24K) 128x64
    __shared__ int ts_s[64];

    if (tid < 64) {
        int s = tt * 64 + tid;
        ts_s[tid] = (s < nt) ? tok[e * CAP + s] : 0;
    }
    __syncthreads();

    f32x4 acc[2][4];
#pragma unroll
    for (int mi = 0; mi < 2; ++mi)
#pragma unroll
        for (int nj = 0; nj < 4; ++nj) acc[mi][nj] = (f32x4){0.f,0.f,0.f,0.f};

    const char* w1row = w1b + (size_t)(d_OFF[e] + n0) * 2048;

    auto STAGE = [&](int buf, int ks) {
        const int k0b = ks * 128;
#pragma unroll
        for (int j = 0; j < 6; ++j) {
            const int flat = j * 4096 + tid * 16;
            char* dst = lds[buf] + flat;
            if (flat < 8192) {
                int r = flat >> 7, cb = flat & 127;
                gload_lds16(xb + (size_t)ts_s[r] * 2048 + k0b + (cb ^ ((r & 7) << 4)), dst);
            } else {
                int f2 = flat - 8192, n = f2 >> 7, cb = f2 & 127;
                gload_lds16(w1row + (size_t)n * 2048 + k0b + (cb ^ ((n & 7) << 4)), dst);
            }
        }
    };
    auto COMPUTE = [&](int buf) {
        const char* LA = lds[buf];
        const char* LB = lds[buf] + 8192;
#pragma unroll
        for (int ksl = 0; ksl < 2; ++ksl) {
            const int kb = ksl * 64 + (lane >> 4) * 16;
            bf16x8 a[2], b[4];
#pragma unroll
            for (int mi = 0; mi < 2; ++mi) {
                int row = wr * 32 + mi * 16 + (lane & 15);
                a[mi] = *(const bf16x8*)(LA + row * 128 + (kb ^ ((row & 7) << 4)));
            }
#pragma unroll
            for (int nj = 0; nj < 4; ++nj) {
                int n = wc * 64 + nj * 16 + (lane & 15);
                b[nj] = *(const bf16x8*)(LB + n * 128 + (kb ^ ((n & 7) << 4)));
            }
#pragma unroll
            for (int mi = 0; mi < 2; ++mi)
#pragma unroll
                for (int nj = 0; nj < 4; ++nj)
                    acc[mi][nj] = __builtin_amdgcn_mfma_f32_16x16x32_bf16(
                        a[mi], b[nj], acc[mi][nj], 0, 0, 0);
        }
    };

    STAGE(0, 0);
    int cur = 0;
    for (int ks = 0; ks < 16; ++ks) {
        if (ks + 1 < 16) {
            STAGE(cur ^ 1, ks + 1);
            asm volatile("s_waitcnt vmcnt(6)" ::: "memory");   // cur done; next in flight
        } else {
            asm volatile("s_waitcnt vmcnt(0)" ::: "memory");
        }
        __builtin_amdgcn_s_barrier();
        __builtin_amdgcn_sched_barrier(0);
        COMPUTE(cur);
        __builtin_amdgcn_sched_barrier(0);
        __builtin_amdgcn_s_barrier();
        cur ^= 1;
    }

    const size_t hbase = (size_t)d_OFF[e] * CAPH;
#pragma unroll
    for (int mi = 0; mi < 2; ++mi)
#pragma unroll
        for (int q = 0; q < 4; ++q) {
            int row  = wr * 32 + mi * 16 + (lane >> 4) * 4 + q;
            int slot = tt * 64 + row;
            __hip_bfloat16* hp = H + hbase + (size_t)slot * we + n0 + wc * 64 + (lane & 15);
#pragma unroll
            for (int nj = 0; nj < 4; ++nj) {
                float v = fmaxf(acc[mi][nj][q], 0.f);
                hp[nj * 16] = __float2bfloat16(v * v);
            }
        }
}

// -------- GEMM2: Y[2t+k] = H @ W2 (raw f32 partials, no atomics) --------
__global__ __launch_bounds__(256) void gemm2_kernel(
    const char* __restrict__ Hb, const char* __restrict__ w2b,
    const int* __restrict__ cnt, const int* __restrict__ slotk,
    float* __restrict__ Y)
{
    int bx0 = blockIdx.x;
    int bx = (bx0 & 7) * 256 + (bx0 >> 3);   // 2048 = 8*256
    int e, tt, nT;
    if (bx < 1024) {                          // wide experts first (32 K-steps)
        e = 4 + (bx >> 8); int r = bx & 255; tt = r >> 3; nT = r & 7;
    } else {
        int b2 = bx - 1024; e = b2 >> 8; int r = b2 & 255; tt = r >> 3; nT = r & 7;
    }
    const int nt = cnt[e << 5];
    if (tt * 64 >= nt) return;

    const int we  = d_WID[e];
    const int n0  = nT * 128;
    const int tid = threadIdx.x;
    const int wv  = tid >> 6, lane = tid & 63;
    const int wr  = wv >> 1, wc = wv & 1;

    __shared__ __align__(16) char lds[2][24576];
    __shared__ int yk_s[64];

    if (tid < 64) {
        int s = tt * 64 + tid;
        yk_s[tid] = (s < nt) ? slotk[e * CAP + s] : 0;
    }
    __syncthreads();

    f32x4 acc[2][4];
#pragma unroll
    for (int mi = 0; mi < 2; ++mi)
#pragma unroll
        for (int nj = 0; nj < 4; ++nj) acc[mi][nj] = (f32x4){0.f,0.f,0.f,0.f};

    const char* Habase = Hb + ((size_t)d_OFF[e] * CAPH + (size_t)tt * 64 * we) * 2;
    const char* w2base = w2b + ((size_t)n0 * TOTAL_W + d_OFF[e]) * 2;
    const int   ksteps = we >> 6;

    auto STAGE = [&](int buf, int ks) {
        const int k0b = ks * 128;
#pragma unroll
        for (int j = 0; j < 6; ++j) {
            const int flat = j * 4096 + tid * 16;
            char* dst = lds[buf] + flat;
            if (flat < 8192) {
                int r = flat >> 7, cb = flat & 127;
                gload_lds16(Habase + (size_t)r * (we * 2) + k0b + (cb ^ ((r & 7) << 4)), dst);
            } else {
                int f2 = flat - 8192, n = f2 >> 7, cb = f2 & 127;
                gload_lds16(w2base + (size_t)n * (TOTAL_W * 2) + k0b + (cb ^ ((n & 7) << 4)), dst);
            }
        }
    };
    auto COMPUTE = [&](int buf) {
        const char* LA = lds[buf];
        const char* LB = lds[buf] + 8192;
#pragma unroll
        for (int ksl = 0; ksl < 2; ++ksl) {
            const int kb = ksl * 64 + (lane >> 4) * 16;
            bf16x8 a[2], b[4];
#pragma unroll
            for (int mi = 0; mi < 2; ++mi) {
                int row = wr * 32 + mi * 16 + (lane & 15);
                a[mi] = *(const bf16x8*)(LA + row * 128 + (kb ^ ((row & 7) << 4)));
            }
#pragma unroll
            for (int nj = 0; nj < 4; ++nj) {
                int n = wc * 64 + nj * 16 + (lane & 15);
                b[nj] = *(const bf16x8*)(LB + n * 128 + (kb ^ ((n & 7) << 4)));
            }
#pragma unroll
            for (int mi = 0; mi < 2; ++mi)
#pragma unroll
                for (int nj = 0; nj < 4; ++nj)
                    acc[mi][nj] = __builtin_amdgcn_mfma_f32_16x16x32_bf16(
                        a[mi], b[nj], acc[mi][nj], 0, 0, 0);
        }
    };

    STAGE(0, 0);
    int cur = 0;
    for (int ks = 0; ks < ksteps; ++ks) {
        if (ks + 1 < ksteps) {
            STAGE(cur ^ 1, ks + 1);
            asm volatile("s_waitcnt vmcnt(6)" ::: "memory");
        } else {
            asm volatile("s_waitcnt vmcnt(0)" ::: "memory");
        }
        __builtin_amdgcn_s_barrier();
        __builtin_amdgcn_sched_barrier(0);
        COMPUTE(cur);
        __builtin_amdgcn_sched_barrier(0);
        __builtin_amdgcn_s_barrier();
        cur ^= 1;
    }

#pragma unroll
    for (int mi = 0; mi < 2; ++mi)
#pragma unroll
        for (int q = 0; q < 4; ++q) {
            int row  = wr * 32 + mi * 16 + (lane >> 4) * 4 + q;
            int slot = tt * 64 + row;
            if (slot < nt) {
                float* yp = Y + (size_t)yk_s[row] * D_EMBD + n0 + wc * 64 + (lane & 15);
#pragma unroll
                for (int nj = 0; nj < 4; ++nj)
                    yp[nj * 16] = acc[mi][nj][q];
            }
        }
}

// -------- gather: out[t] = w0*Y[2t] + w1*Y[2t+1] --------
__global__ __launch_bounds__(256) void gather_kernel(
    const float* __restrict__ Y, const float* __restrict__ wgt2,
    float* __restrict__ out)
{
    const int t = blockIdx.x, tid = threadIdx.x;
    const float w0 = wgt2[t * 2], w1 = wgt2[t * 2 + 1];
    const float4 y0 = reinterpret_cast<const float4*>(Y + (size_t)(t * 2) * D_EMBD)[tid];
    const float4 y1 = reinterpret_cast<const float4*>(Y + (size_t)(t * 2 + 1) * D_EMBD)[tid];
    float4 o;
    o.x = w0 * y0.x + w1 * y1.x;  o.y = w0 * y0.y + w1 * y1.y;
    o.z = w0 * y0.z + w1 * y1.z;  o.w = w0 * y0.w + w1 * y1.w;
    reinterpret_cast<float4*>(out + (size_t)t * D_EMBD)[tid] = o;
}

// -------- fp32 fallback (if ws too small) --------
__global__ __launch_bounds__(256, 3) void moe_group_kernel(
    const float* __restrict__ x, const float* __restrict__ w1,
    const float* __restrict__ w2, const int* __restrict__ cnt,
    const int* __restrict__ tok, const float* __restrict__ wgtl,
    float* __restrict__ out)
{
    int e, tt, colh, wh, nwh;
    int bx = blockIdx.x;
    if (bx < 1024) { e = bx >> 8; int rem = bx & 255; wh = rem & 1; colh = (rem >> 1) & 1; tt = rem >> 2; nwh = 2; }
    else { int b2 = bx - 1024; e = 4 + (b2 >> 9); int rem = b2 & 511; wh = rem & 3; colh = (rem >> 2) & 1; tt = rem >> 3; nwh = 4; }
    const int nt = cnt[e << 5];
    if (tt * 32 >= nt) return;

    const int tid = threadIdx.x;
    const int off = d_OFF[e];
    const int wtn = d_WID[e] >> 7;
    const int wpb = wtn / nwh;
    const int wt0 = wh * wpb;

    __shared__ float xs[128][36];
    __shared__ float hs[128][36];
    __shared__ int   ts_s[32];
    __shared__ float wg_s[32];

    if (tid < 32) {
        int s = tt * 32 + tid;
        ts_s[tid] = (s < nt) ? tok[e * CAP + s] : 0;
        wg_s[tid] = (s < nt) ? wgtl[e * CAP + s] : 0.f;
    }

    const int tg = tid >> 5, cg = tid & 31;
    float acc_dn[4][16];
#pragma unroll
    for (int a = 0; a < 4; ++a)
#pragma unroll
        for (int m = 0; m < 16; ++m) acc_dn[a][m] = 0.f;

    for (int wt = wt0; wt < wt0 + wpb; ++wt) {
        float au[4][4];
#pragma unroll
        for (int a = 0; a < 4; ++a)
#pragma unroll
            for (int b = 0; b < 4; ++b) au[a][b] = 0.f;
        const int cw1 = off + wt * 128 + cg * 4;
        for (int dc = 0; dc < 8; ++dc) {
            const int d0 = dc * 128;
            __syncthreads();
#pragma unroll
            for (int r = 0; r < 16; ++r) {
                int flat = r * 256 + tid, ii = flat & 127, t = flat >> 7;
                xs[ii][t] = x[(size_t)ts_s[t] * D_EMBD + d0 + ii];
            }
            __syncthreads();
            const float* pw = w1 + (size_t)d0 * TOTAL_W + cw1;
            for (int ii = 0; ii < 128; ++ii) {
                const float4 xv = *reinterpret_cast<const float4*>(&xs[ii][tg * 4]);
                const float4 wv = *reinterpret_cast<const float4*>(pw);
                pw += TOTAL_W;
                const float xa[4] = {xv.x, xv.y, xv.z, xv.w};
                const float wb[4] = {wv.x, wv.y, wv.z, wv.w};
#pragma unroll
                for (int a = 0; a < 4; ++a)
#pragma unroll
                    for (int b = 0; b < 4; ++b) au[a][b] += xa[a] * wb[b];
            }
        }
#pragma unroll
        for (int b = 0; b < 4; ++b) {
            float4 v;
            float r0 = fmaxf(au[0][b], 0.f), r1 = fmaxf(au[1][b], 0.f);
            float r2 = fmaxf(au[2][b], 0.f), r3 = fmaxf(au[3][b], 0.f);
            v.x = r0 * r0; v.y = r1 * r1; v.z = r2 * r2; v.w = r3 * r3;
            *reinterpret_cast<float4*>(&hs[cg * 4 + b][tg * 4]) = v;
        }
        __syncthreads();
        const float* pw2 = w2 + (size_t)(off + wt * 128) * D_EMBD + colh * 512 + cg * 4;
        for (int j = 0; j < 128; ++j) {
            const float4 hv = *reinterpret_cast<const float4*>(&hs[j][tg * 4]);
            const float ha[4] = {hv.x, hv.y, hv.z, hv.w};
            const float* row = pw2 + (size_t)j * D_EMBD;
#pragma unroll
            for (int b = 0; b < 4; ++b) {
                const float4 wv = *reinterpret_cast<const float4*>(row + b * 128);
                const float wq[4] = {wv.x, wv.y, wv.z, wv.w};
#pragma unroll
                for (int a = 0; a < 4; ++a)
#pragma unroll
                    for (int q = 0; q < 4; ++q)
                        acc_dn[a][b * 4 + q] += ha[a] * wq[q];
            }
        }
        __syncthreads();
    }
#pragma unroll
    for (int a = 0; a < 4; ++a) {
        const int   t  = ts_s[tg * 4 + a];
        const float wg = wg_s[tg * 4 + a];
        float* ot = out + (size_t)t * D_EMBD + colh * 512 + cg * 4;
#pragma unroll
        for (int b = 0; b < 4; ++b)
#pragma unroll
            for (int q = 0; q < 4; ++q)
                atomicAdd(&ot[b * 128 + q], wg * acc_dn[a][b * 4 + q]);
    }
}

extern "C" void kernel_launch(void* const* d_in, const int* in_sizes, int n_in,
                              void* d_out, int out_size, void* d_ws, size_t ws_size,
                              hipStream_t stream) {
    const float* x  = (const float*)d_in[0];
    const float* rw = (const float*)d_in[1];
    const float* w1 = (const float*)d_in[2];
    const float* w2 = (const float*)d_in[3];
    float* out = (float*)d_out;

    char*  ws    = (char*)d_ws;
    int*   cnt   = (int*)ws;                    // 8 counters, 128B apart
    int*   tokl  = (int*)(ws + WS_TOK);
    int*   slotk = (int*)(ws + WS_SLK);
    float* wgtl  = (float*)(ws + WS_WGT);
    float* wgt2  = (float*)(ws + WS_WG2);

    if (ws_size >= WS_END) {
        __hip_bfloat16* xb  = (__hip_bfloat16*)(ws + WS_XB);
        __hip_bfloat16* w1b = (__hip_bfloat16*)(ws + WS_W1B);
        __hip_bfloat16* w2b = (__hip_bfloat16*)(ws + WS_W2B);
        __hip_bfloat16* H   = (__hip_bfloat16*)(ws + WS_H);
        float*          Y   = (float*)(ws + WS_Y);   // aliases XB/W1B (dead post-gemm1)

        zero_kernel<<<1, 64, 0, stream>>>(cnt);
        prep2_kernel<<<7232, 256, 0, stream>>>(x, rw, w1, w2, cnt, tokl, slotk, wgtl, wgt2,
                                               xb, w1b, w2b);
        gemm1_kernel<<<3072, 256, 0, stream>>>((const char*)xb, (const char*)w1b, cnt, tokl, H);
        gemm2_kernel<<<2048, 256, 0, stream>>>((const char*)H, (const char*)w2b, cnt, slotk, Y);
        gather_kernel<<<T_TOKENS, 256, 0, stream>>>(Y, wgt2, out);
    } else {
        hipMemsetAsync(d_ws, 0, 1024, stream);
        hipMemsetAsync(d_out, 0, (size_t)out_size * sizeof(float), stream);
        router2_kernel<<<T_TOKENS / 32, 256, 0, stream>>>(x, rw, cnt, tokl, slotk, wgtl, wgt2);
        moe_group_kernel<<<1024 + 2048, 256, 0, stream>>>(x, w1, w2, cnt, tokl, wgtl, out);
    }
}